// Round 8
// baseline (211.187 us; speedup 1.0000x reference)
//
#include <hip/hip_runtime.h>
#include <hip/hip_bf16.h>
#include <hip/hip_fp16.h>

// GIN via linearity: agg(x)@W == agg(x@W). Per layer: z = X@W (MFMA fp16,
// fp32 accum), then h = relu(z + gather_sum(z) + b) via on-device CSR.
// CSR: single-pass fixed-capacity coarse buckets (dst>>8, CAP slots each),
// packed 4B staging (src:16 | dst&255:16), LDS-local per-bucket finalize.
// Gather is channel-split 2-way: half = blockIdx&1 maps halves to even/odd
// XCDs (round-robin dispatch) so each XCD L2 holds only 3.2 MB of Z.

#define N_FEAT 64
#define CHUNK 4096
#define CAP 6144   // slots per coarse bucket (mean fill 4096, >30 sigma slack)

typedef _Float16 f16;
typedef _Float16 half8 __attribute__((ext_vector_type(8)));
typedef float float4v __attribute__((ext_vector_type(4)));

__device__ inline f16 cvt_f16(float v) { return (f16)v; }
__device__ inline f16 cvt_f16(f16 v) { return v; }

// ---- GEMM via MFMA: 64 rows/block, 4 waves; wave w = 16-row strip ----
template <typename TIN>
__global__ void gemm_mfma(const TIN* __restrict__ X, const float* __restrict__ W,
                          f16* __restrict__ Z, int nrows) {
    __shared__ f16 sX[64][72];
    __shared__ f16 sWT[64][72];
    int t = threadIdx.x;
    int base = blockIdx.x * 64;
    for (int idx = t; idx < 4096; idx += 256) {
        int k = idx >> 6, n = idx & 63;
        sWT[n][k] = (f16)W[idx];               // W[k][n] -> sWT[n][k]
    }
    for (int idx = t; idx < 4096; idx += 256) {
        int r = idx >> 6, c = idx & 63;
        int row = base + r;
        sX[r][c] = (row < nrows) ? cvt_f16(X[(size_t)row * 64 + c]) : (f16)0.f;
    }
    __syncthreads();
    int wave = t >> 6;
    int lane = t & 63;
    int quad = lane >> 4;
    int m16 = lane & 15;
    half8 a0 = *(const half8*)&sX[wave * 16 + m16][quad * 8];
    half8 a1 = *(const half8*)&sX[wave * 16 + m16][32 + quad * 8];
    float4v acc[4];
#pragma unroll
    for (int C = 0; C < 4; ++C) {
        half8 b0 = *(const half8*)&sWT[C * 16 + m16][quad * 8];
        half8 b1 = *(const half8*)&sWT[C * 16 + m16][32 + quad * 8];
        float4v d = {0.f, 0.f, 0.f, 0.f};
        d = __builtin_amdgcn_mfma_f32_16x16x32_f16(a0, b0, d, 0, 0, 0);
        d = __builtin_amdgcn_mfma_f32_16x16x32_f16(a1, b1, d, 0, 0, 0);
        acc[C] = d;
    }
#pragma unroll
    for (int reg = 0; reg < 4; ++reg) {
        int row = base + wave * 16 + quad * 4 + reg;
        if (row < nrows) {
#pragma unroll
            for (int C = 0; C < 4; ++C)
                Z[(size_t)row * 64 + C * 16 + m16] = (f16)acc[C][reg];
        }
    }
}

// ---- CSR pass A: coarse-bucket packed edges into fixed-capacity regions ----
// pack = src(16b) | (dst&255)<<16    (requires N <= 65536)
__global__ void bucket_scatter(const int* __restrict__ src, const int* __restrict__ dst,
                               int* __restrict__ ccur, int* __restrict__ staging, int E) {
    __shared__ int epack[CHUNK];
    __shared__ int ebkt[CHUNK];
    __shared__ int hist[256];
    __shared__ int base[256];
    int t = threadIdx.x;
    int begin = blockIdx.x * CHUNK;
    int cnt = min(CHUNK, E - begin);
    hist[t] = 0;
    __syncthreads();
    for (int i = t; i < cnt; i += 256) {
        int d = dst[begin + i];
        int s = src[begin + i];
        epack[i] = (s & 0xFFFF) | ((d & 255) << 16);
        ebkt[i] = d >> 8;
        atomicAdd(&hist[d >> 8], 1);
    }
    __syncthreads();
    int h = hist[t];
    if (h > 0) base[t] = atomicAdd(&ccur[t], h);
    hist[t] = 0;
    __syncthreads();
    for (int i = t; i < cnt; i += 256) {
        int b = ebkt[i];
        int off = base[b] + atomicAdd(&hist[b], 1);
        if (off < CAP) staging[(size_t)b * CAP + off] = epack[i];
    }
}

// ---- CSR pass B: per-bucket hist+scan+scatter fully in LDS ----
__global__ void bucket_finalize(const int* __restrict__ staging, const int* __restrict__ ccur,
                                int2* __restrict__ rowse, int* __restrict__ col, int N) {
    __shared__ int edges[CAP];
    __shared__ int hist[256];
    __shared__ int scan[256];
    __shared__ int cur[256];
    int b = blockIdx.x, t = threadIdx.x;
    int cnt = min(ccur[b], CAP);
    int sbase = b * CAP;
    hist[t] = 0;
    __syncthreads();
    for (int i = t; i < cnt; i += 256) {
        int e = staging[(size_t)sbase + i];
        edges[i] = e;
        atomicAdd(&hist[(e >> 16) & 255], 1);
    }
    __syncthreads();
    int v = hist[t];
    scan[t] = v;
    __syncthreads();
    for (int off = 1; off < 256; off <<= 1) {
        int u = (t >= off) ? scan[t - off] : 0;
        __syncthreads();
        scan[t] += u;
        __syncthreads();
    }
    int excl = scan[t] - v;
    cur[t] = excl;
    int node = b * 256 + t;
    if (node < N) rowse[node] = make_int2(sbase + excl, sbase + excl + v);
    __syncthreads();
    for (int i = t; i < cnt; i += 256) {
        int e = edges[i];
        int pos = sbase + atomicAdd(&cur[(e >> 16) & 255], 1);
        col[pos] = e & 0xFFFF;
    }
}

// ---- gather + bias + relu; channel-split 2-way; 1 wave = (node, half) ----
// half = blockIdx&1 -> even/odd XCD locality. 8 groups x 8 lanes x 8B = 64B row.
__global__ void gather_relu(const f16* __restrict__ Z, const int2* __restrict__ rowse,
                            const int* __restrict__ col, const float* __restrict__ bias,
                            f16* __restrict__ H, int n) {
    int wave = threadIdx.x >> 6;
    int node = (blockIdx.x >> 1) * 4 + wave;
    if (node >= n) return;
    int half = blockIdx.x & 1;
    int lane = threadIdx.x & 63;
    int g = lane >> 3;                 // 0..7 edge group
    int l = lane & 7;                  // 0..7 channel chunk (8B = 4 ch)
    int rb = half * 8 + l;             // float2 index within row
    int2 se = rowse[node];
    int lo = se.x, hi = se.y;
    const float2* Z2 = reinterpret_cast<const float2*>(Z);
    float ax = 0.f, ay = 0.f, az = 0.f, aw = 0.f;
    int j = lo + g;
    while (j + 8 < hi) {
        int s0 = col[j], s1 = col[j + 8];
        float2 r0 = Z2[(size_t)s0 * 16 + rb];
        float2 r1 = Z2[(size_t)s1 * 16 + rb];
        float2 f;
        f = __half22float2(*(__half2*)&r0.x); ax += f.x; ay += f.y;
        f = __half22float2(*(__half2*)&r0.y); az += f.x; aw += f.y;
        f = __half22float2(*(__half2*)&r1.x); ax += f.x; ay += f.y;
        f = __half22float2(*(__half2*)&r1.y); az += f.x; aw += f.y;
        j += 16;
    }
    for (; j < hi; j += 8) {
        float2 r = Z2[(size_t)col[j] * 16 + rb];
        float2 f0 = __half22float2(*(__half2*)&r.x);
        float2 f1 = __half22float2(*(__half2*)&r.y);
        ax += f0.x; ay += f0.y; az += f1.x; aw += f1.y;
    }
    ax += __shfl_xor(ax, 8);  ay += __shfl_xor(ay, 8);
    az += __shfl_xor(az, 8);  aw += __shfl_xor(aw, 8);
    ax += __shfl_xor(ax, 16); ay += __shfl_xor(ay, 16);
    az += __shfl_xor(az, 16); aw += __shfl_xor(aw, 16);
    ax += __shfl_xor(ax, 32); ay += __shfl_xor(ay, 32);
    az += __shfl_xor(az, 32); aw += __shfl_xor(aw, 32);
    if (g == 0) {
        float2 sr = Z2[(size_t)node * 16 + rb];
        float2 fs0 = __half22float2(*(__half2*)&sr.x);
        float2 fs1 = __half22float2(*(__half2*)&sr.y);
        float4 b = reinterpret_cast<const float4*>(bias)[rb];
        __half2 o0 = __floats2half2_rn(fmaxf(fs0.x + ax + b.x, 0.f),
                                       fmaxf(fs0.y + ay + b.y, 0.f));
        __half2 o1 = __floats2half2_rn(fmaxf(fs1.x + az + b.z, 0.f),
                                       fmaxf(fs1.y + aw + b.w, 0.f));
        float2 outv;
        *(__half2*)&outv.x = o0;
        *(__half2*)&outv.y = o1;
        reinterpret_cast<float2*>(H)[(size_t)node * 16 + rb] = outv;
    }
}

// ---- fused mean-pool + linear head; 256 threads/graph ----
__global__ void pool_head(const f16* __restrict__ H, const int* __restrict__ batch,
                          const float* __restrict__ W3, const float* __restrict__ b3,
                          float* __restrict__ out, int n, int ncls) {
    int gidx = blockIdx.x;
    __shared__ int bounds[2];
    __shared__ float sred[4 * 64];
    __shared__ float row[64];
    int t = threadIdx.x;                 // 0..255
    int w = t >> 6;
    int lane = t & 63;
    int g = lane >> 4, l = lane & 15;
    if (t < 2) {
        int target = gidx + t;
        int lo = 0, hi = n;
        while (lo < hi) { int m = (lo + hi) >> 1; if (batch[m] < target) lo = m + 1; else hi = m; }
        bounds[t] = lo;
    }
    __syncthreads();
    int lo = bounds[0], hi = bounds[1];
    const float2* H2 = reinterpret_cast<const float2*>(H);
    float ax = 0.f, ay = 0.f, az = 0.f, aw = 0.f;
    for (int i = lo + (w * 4 + g); i < hi; i += 16) {
        float2 raw = H2[(size_t)i * 16 + l];
        float2 f0 = __half22float2(*(__half2*)&raw.x);
        float2 f1 = __half22float2(*(__half2*)&raw.y);
        ax += f0.x; ay += f0.y; az += f1.x; aw += f1.y;
    }
    ax += __shfl_xor(ax, 16); ay += __shfl_xor(ay, 16);
    az += __shfl_xor(az, 16); aw += __shfl_xor(aw, 16);
    ax += __shfl_xor(ax, 32); ay += __shfl_xor(ay, 32);
    az += __shfl_xor(az, 32); aw += __shfl_xor(aw, 32);
    if (g == 0) {
        sred[w * 64 + l * 4 + 0] = ax;
        sred[w * 64 + l * 4 + 1] = ay;
        sred[w * 64 + l * 4 + 2] = az;
        sred[w * 64 + l * 4 + 3] = aw;
    }
    __syncthreads();
    if (w == 0) {
        float s = sred[lane] + sred[64 + lane] + sred[128 + lane] + sred[192 + lane];
        row[lane] = s / fmaxf((float)(hi - lo), 1.0f);
    }
    __syncthreads();
    if (t < ncls) {
        float o = b3[t];
#pragma unroll
        for (int k = 0; k < 64; ++k) o += row[k] * W3[k * ncls + t];
        out[gidx * ncls + t] = o;
    }
}

extern "C" void kernel_launch(void* const* d_in, const int* in_sizes, int n_in,
                              void* d_out, int out_size, void* d_ws, size_t ws_size,
                              hipStream_t stream) {
    const float* x     = (const float*)d_in[0];
    const int*   ei    = (const int*)d_in[1];   // [2, E]
    const int*   batch = (const int*)d_in[2];
    const float* W1    = (const float*)d_in[3];
    const float* b1    = (const float*)d_in[4];
    const float* W2    = (const float*)d_in[5];
    const float* b2    = (const float*)d_in[6];
    const float* W3    = (const float*)d_in[7];
    const float* b3    = (const float*)d_in[8];
    float* out = (float*)d_out;

    const int N = in_sizes[0] / N_FEAT;       // 50000
    const int E = in_sizes[1] / 2;            // 800000
    const int NCLS = 10;
    const int G = out_size / NCLS;            // 500
    const int* src = ei;
    const int* dst = ei + E;
    const int nb = (N + 255) / 256;           // 196 coarse buckets

    // workspace layout
    int*  staging = (int*)d_ws;                           // nb*CAP packed
    int2* rowse   = (int2*)(staging + (size_t)nb * CAP);  // N
    int*  col     = (int*)(rowse + N);                    // nb*CAP
    int*  ccur    = col + (size_t)nb * CAP;               // 256
    f16*  zbuf    = (f16*)(ccur + 256);                   // N*64
    f16*  hbuf    = zbuf + (size_t)N * 64;                // N*64

    const int gemmGrid = (N + 63) / 64;
    const int gatherGrid = 2 * ((N + 3) / 4);
    const int scatGrid = (E + CHUNK - 1) / CHUNK;

    // ---- build CSR ----
    hipMemsetAsync(ccur, 0, 256 * sizeof(int), stream);
    bucket_scatter<<<scatGrid, 256, 0, stream>>>(src, dst, ccur, staging, E);
    bucket_finalize<<<nb, 256, 0, stream>>>(staging, ccur, rowse, col, N);

    // ---- layer 1 ----
    gemm_mfma<float><<<gemmGrid, 256, 0, stream>>>(x, W1, zbuf, N);
    gather_relu<<<gatherGrid, 256, 0, stream>>>(zbuf, rowse, col, b1, hbuf, N);

    // ---- layer 2 ----
    gemm_mfma<f16><<<gemmGrid, 256, 0, stream>>>(hbuf, W2, zbuf, N);
    gather_relu<<<gatherGrid, 256, 0, stream>>>(zbuf, rowse, col, b2, hbuf, N);

    // ---- pool + head ----
    pool_head<<<G, 256, 0, stream>>>(hbuf, batch, W3, b3, out, N, NCLS);
}

// Round 9
// 190.255 us; speedup vs baseline: 1.1100x; 1.1100x over previous
//
#include <hip/hip_runtime.h>
#include <hip/hip_bf16.h>
#include <hip/hip_fp16.h>

// GIN via linearity: agg(x)@W == agg(x@W). Per layer: z = X@W (MFMA fp16,
// fp32 accum), then h = relu(z + gather_sum(z) + b) via on-device CSR.
// CSR: single-pass fixed-capacity coarse buckets (dst>>8, CAP slots each),
// packed 4B staging (src:16 | dst&255:16), LDS-local per-bucket finalize.
// Gather: 1 wave/node, full 128B row reads, 32 predicated loads in flight
// (r8's channel-split regressed: doubled index traffic, halved request size).

#define N_FEAT 64
#define CHUNK 4096
#define CAP 6144   // slots per coarse bucket (mean fill 4096, >30 sigma slack)

typedef _Float16 f16;
typedef _Float16 half8 __attribute__((ext_vector_type(8)));
typedef float float4v __attribute__((ext_vector_type(4)));

__device__ inline f16 cvt_f16(float v) { return (f16)v; }
__device__ inline f16 cvt_f16(f16 v) { return v; }

// ---- GEMM via MFMA: 64 rows/block, 4 waves; wave w = 16-row strip ----
template <typename TIN>
__global__ void gemm_mfma(const TIN* __restrict__ X, const float* __restrict__ W,
                          f16* __restrict__ Z, int nrows) {
    __shared__ f16 sX[64][72];
    __shared__ f16 sWT[64][72];
    int t = threadIdx.x;
    int base = blockIdx.x * 64;
    for (int idx = t; idx < 4096; idx += 256) {
        int k = idx >> 6, n = idx & 63;
        sWT[n][k] = (f16)W[idx];               // W[k][n] -> sWT[n][k]
    }
    for (int idx = t; idx < 4096; idx += 256) {
        int r = idx >> 6, c = idx & 63;
        int row = base + r;
        sX[r][c] = (row < nrows) ? cvt_f16(X[(size_t)row * 64 + c]) : (f16)0.f;
    }
    __syncthreads();
    int wave = t >> 6;
    int lane = t & 63;
    int quad = lane >> 4;
    int m16 = lane & 15;
    half8 a0 = *(const half8*)&sX[wave * 16 + m16][quad * 8];
    half8 a1 = *(const half8*)&sX[wave * 16 + m16][32 + quad * 8];
    float4v acc[4];
#pragma unroll
    for (int C = 0; C < 4; ++C) {
        half8 b0 = *(const half8*)&sWT[C * 16 + m16][quad * 8];
        half8 b1 = *(const half8*)&sWT[C * 16 + m16][32 + quad * 8];
        float4v d = {0.f, 0.f, 0.f, 0.f};
        d = __builtin_amdgcn_mfma_f32_16x16x32_f16(a0, b0, d, 0, 0, 0);
        d = __builtin_amdgcn_mfma_f32_16x16x32_f16(a1, b1, d, 0, 0, 0);
        acc[C] = d;
    }
#pragma unroll
    for (int reg = 0; reg < 4; ++reg) {
        int row = base + wave * 16 + quad * 4 + reg;
        if (row < nrows) {
#pragma unroll
            for (int C = 0; C < 4; ++C)
                Z[(size_t)row * 64 + C * 16 + m16] = (f16)acc[C][reg];
        }
    }
}

// ---- CSR pass A: coarse-bucket packed edges into fixed-capacity regions ----
// pack = src(16b) | (dst&255)<<16    (requires N <= 65536)
__global__ void bucket_scatter(const int* __restrict__ src, const int* __restrict__ dst,
                               int* __restrict__ ccur, int* __restrict__ staging, int E) {
    __shared__ int epack[CHUNK];
    __shared__ int ebkt[CHUNK];
    __shared__ int hist[256];
    __shared__ int base[256];
    int t = threadIdx.x;
    int begin = blockIdx.x * CHUNK;
    int cnt = min(CHUNK, E - begin);
    hist[t] = 0;
    __syncthreads();
    for (int i = t; i < cnt; i += 256) {
        int d = dst[begin + i];
        int s = src[begin + i];
        epack[i] = (s & 0xFFFF) | ((d & 255) << 16);
        ebkt[i] = d >> 8;
        atomicAdd(&hist[d >> 8], 1);
    }
    __syncthreads();
    int h = hist[t];
    if (h > 0) base[t] = atomicAdd(&ccur[t], h);
    hist[t] = 0;
    __syncthreads();
    for (int i = t; i < cnt; i += 256) {
        int b = ebkt[i];
        int off = base[b] + atomicAdd(&hist[b], 1);
        if (off < CAP) staging[(size_t)b * CAP + off] = epack[i];
    }
}

// ---- CSR pass B: per-bucket hist+scan+scatter fully in LDS ----
__global__ void bucket_finalize(const int* __restrict__ staging, const int* __restrict__ ccur,
                                int2* __restrict__ rowse, int* __restrict__ col, int N) {
    __shared__ int edges[CAP];
    __shared__ int hist[256];
    __shared__ int scan[256];
    __shared__ int cur[256];
    int b = blockIdx.x, t = threadIdx.x;
    int cnt = min(ccur[b], CAP);
    int sbase = b * CAP;
    hist[t] = 0;
    __syncthreads();
    for (int i = t; i < cnt; i += 256) {
        int e = staging[(size_t)sbase + i];
        edges[i] = e;
        atomicAdd(&hist[(e >> 16) & 255], 1);
    }
    __syncthreads();
    int v = hist[t];
    scan[t] = v;
    __syncthreads();
    for (int off = 1; off < 256; off <<= 1) {
        int u = (t >= off) ? scan[t - off] : 0;
        __syncthreads();
        scan[t] += u;
        __syncthreads();
    }
    int excl = scan[t] - v;
    cur[t] = excl;
    int node = b * 256 + t;
    if (node < N) rowse[node] = make_int2(sbase + excl, sbase + excl + v);
    __syncthreads();
    for (int i = t; i < cnt; i += 256) {
        int e = edges[i];
        int pos = sbase + atomicAdd(&cur[(e >> 16) & 255], 1);
        col[pos] = e & 0xFFFF;
    }
}

// ---- gather + bias + relu; 1 wave/node; 32 predicated loads in flight ----
// group g (lane>>4) covers edges (j-lo)%4==g; lane l (lane&15) owns 8B chunk.
__global__ void gather_relu(const f16* __restrict__ Z, const int2* __restrict__ rowse,
                            const int* __restrict__ col, const float* __restrict__ bias,
                            f16* __restrict__ H, int n) {
    int node = (int)((blockIdx.x * blockDim.x + threadIdx.x) >> 6);
    if (node >= n) return;
    int lane = threadIdx.x & 63;
    int g = lane >> 4, l = lane & 15;
    int2 se = rowse[node];
    int lo = se.x, hi = se.y;
    const float2* Z2 = reinterpret_cast<const float2*>(Z);
    float ax = 0.f, ay = 0.f, az = 0.f, aw = 0.f;
    // main batch: 32 edges (8 per group), fully predicated, one latency trip
    int idx[8];
#pragma unroll
    for (int i = 0; i < 8; ++i) {
        int j = lo + g + i * 4;
        idx[i] = (j < hi) ? col[j] : -1;
    }
#pragma unroll
    for (int i = 0; i < 8; ++i) {
        if (idx[i] >= 0) {
            float2 r = Z2[(size_t)idx[i] * 16 + l];
            float2 f0 = __half22float2(*(__half2*)&r.x);
            float2 f1 = __half22float2(*(__half2*)&r.y);
            ax += f0.x; ay += f0.y; az += f1.x; aw += f1.y;
        }
    }
    // rare tail (deg > 32): P ~ 1e-4 for Poisson(16)
    for (int j = lo + 32 + g; j < hi; j += 4) {
        float2 r = Z2[(size_t)col[j] * 16 + l];
        float2 f0 = __half22float2(*(__half2*)&r.x);
        float2 f1 = __half22float2(*(__half2*)&r.y);
        ax += f0.x; ay += f0.y; az += f1.x; aw += f1.y;
    }
    ax += __shfl_xor(ax, 16); ay += __shfl_xor(ay, 16);
    az += __shfl_xor(az, 16); aw += __shfl_xor(aw, 16);
    ax += __shfl_xor(ax, 32); ay += __shfl_xor(ay, 32);
    az += __shfl_xor(az, 32); aw += __shfl_xor(aw, 32);
    if (g == 0) {
        float2 sr = Z2[(size_t)node * 16 + l];
        float2 fs0 = __half22float2(*(__half2*)&sr.x);
        float2 fs1 = __half22float2(*(__half2*)&sr.y);
        float4 b = reinterpret_cast<const float4*>(bias)[l];
        __half2 o0 = __floats2half2_rn(fmaxf(fs0.x + ax + b.x, 0.f),
                                       fmaxf(fs0.y + ay + b.y, 0.f));
        __half2 o1 = __floats2half2_rn(fmaxf(fs1.x + az + b.z, 0.f),
                                       fmaxf(fs1.y + aw + b.w, 0.f));
        float2 outv;
        *(__half2*)&outv.x = o0;
        *(__half2*)&outv.y = o1;
        reinterpret_cast<float2*>(H)[(size_t)node * 16 + l] = outv;
    }
}

// ---- fused mean-pool + linear head; 256 threads/graph ----
__global__ void pool_head(const f16* __restrict__ H, const int* __restrict__ batch,
                          const float* __restrict__ W3, const float* __restrict__ b3,
                          float* __restrict__ out, int n, int ncls) {
    int gidx = blockIdx.x;
    __shared__ int bounds[2];
    __shared__ float sred[4 * 64];
    __shared__ float row[64];
    int t = threadIdx.x;                 // 0..255
    int w = t >> 6;
    int lane = t & 63;
    int g = lane >> 4, l = lane & 15;
    if (t < 2) {
        int target = gidx + t;
        int lo = 0, hi = n;
        while (lo < hi) { int m = (lo + hi) >> 1; if (batch[m] < target) lo = m + 1; else hi = m; }
        bounds[t] = lo;
    }
    __syncthreads();
    int lo = bounds[0], hi = bounds[1];
    const float2* H2 = reinterpret_cast<const float2*>(H);
    float ax = 0.f, ay = 0.f, az = 0.f, aw = 0.f;
    for (int i = lo + (w * 4 + g); i < hi; i += 16) {
        float2 raw = H2[(size_t)i * 16 + l];
        float2 f0 = __half22float2(*(__half2*)&raw.x);
        float2 f1 = __half22float2(*(__half2*)&raw.y);
        ax += f0.x; ay += f0.y; az += f1.x; aw += f1.y;
    }
    ax += __shfl_xor(ax, 16); ay += __shfl_xor(ay, 16);
    az += __shfl_xor(az, 16); aw += __shfl_xor(aw, 16);
    ax += __shfl_xor(ax, 32); ay += __shfl_xor(ay, 32);
    az += __shfl_xor(az, 32); aw += __shfl_xor(aw, 32);
    if (g == 0) {
        sred[w * 64 + l * 4 + 0] = ax;
        sred[w * 64 + l * 4 + 1] = ay;
        sred[w * 64 + l * 4 + 2] = az;
        sred[w * 64 + l * 4 + 3] = aw;
    }
    __syncthreads();
    if (w == 0) {
        float s = sred[lane] + sred[64 + lane] + sred[128 + lane] + sred[192 + lane];
        row[lane] = s / fmaxf((float)(hi - lo), 1.0f);
    }
    __syncthreads();
    if (t < ncls) {
        float o = b3[t];
#pragma unroll
        for (int k = 0; k < 64; ++k) o += row[k] * W3[k * ncls + t];
        out[gidx * ncls + t] = o;
    }
}

extern "C" void kernel_launch(void* const* d_in, const int* in_sizes, int n_in,
                              void* d_out, int out_size, void* d_ws, size_t ws_size,
                              hipStream_t stream) {
    const float* x     = (const float*)d_in[0];
    const int*   ei    = (const int*)d_in[1];   // [2, E]
    const int*   batch = (const int*)d_in[2];
    const float* W1    = (const float*)d_in[3];
    const float* b1    = (const float*)d_in[4];
    const float* W2    = (const float*)d_in[5];
    const float* b2    = (const float*)d_in[6];
    const float* W3    = (const float*)d_in[7];
    const float* b3    = (const float*)d_in[8];
    float* out = (float*)d_out;

    const int N = in_sizes[0] / N_FEAT;       // 50000
    const int E = in_sizes[1] / 2;            // 800000
    const int NCLS = 10;
    const int G = out_size / NCLS;            // 500
    const int* src = ei;
    const int* dst = ei + E;
    const int nb = (N + 255) / 256;           // 196 coarse buckets

    // workspace layout
    int*  staging = (int*)d_ws;                           // nb*CAP packed
    int2* rowse   = (int2*)(staging + (size_t)nb * CAP);  // N
    int*  col     = (int*)(rowse + N);                    // nb*CAP
    int*  ccur    = col + (size_t)nb * CAP;               // 256
    f16*  zbuf    = (f16*)(ccur + 256);                   // N*64
    f16*  hbuf    = zbuf + (size_t)N * 64;                // N*64

    const int gemmGrid = (N + 63) / 64;
    const int gatherGrid = (N + 3) / 4;
    const int scatGrid = (E + CHUNK - 1) / CHUNK;

    // ---- build CSR ----
    hipMemsetAsync(ccur, 0, 256 * sizeof(int), stream);
    bucket_scatter<<<scatGrid, 256, 0, stream>>>(src, dst, ccur, staging, E);
    bucket_finalize<<<nb, 256, 0, stream>>>(staging, ccur, rowse, col, N);

    // ---- layer 1 ----
    gemm_mfma<float><<<gemmGrid, 256, 0, stream>>>(x, W1, zbuf, N);
    gather_relu<<<gatherGrid, 256, 0, stream>>>(zbuf, rowse, col, b1, hbuf, N);

    // ---- layer 2 ----
    gemm_mfma<f16><<<gemmGrid, 256, 0, stream>>>(hbuf, W2, zbuf, N);
    gather_relu<<<gatherGrid, 256, 0, stream>>>(zbuf, rowse, col, b2, hbuf, N);

    // ---- pool + head ----
    pool_head<<<G, 256, 0, stream>>>(hbuf, batch, W3, b3, out, N, NCLS);
}